// Round 1
// baseline (200.009 us; speedup 1.0000x reference)
//
#include <hip/hip_runtime.h>

#define IMG      512
#define NIMG     32
#define TX       64
#define TY       16
#define HALO     5
#define KW       11
#define W_IN     (TX + 2*HALO)   /* 74 */
#define H_IN     (TY + 2*HALO)   /* 26 */
#define NPIX     (32.0f * 512.0f * 512.0f)   /* 8388608 */

__global__ void ssim_init_out(float* __restrict__ out) {
    out[0] = 1.0f;
}

__global__ __launch_bounds__(256) void ssim_tile(const float* __restrict__ img1,
                                                 const float* __restrict__ img2,
                                                 float* __restrict__ out) {
    // Normalized 11-tap Gaussian, sigma=1.5 (symmetric)
    constexpr float GW[KW] = {
        0.00102838f, 0.00759876f, 0.03600077f, 0.10936069f, 0.21300553f,
        0.26601174f,
        0.21300553f, 0.10936069f, 0.03600077f, 0.00759876f, 0.00102838f
    };
    constexpr float C1 = 0.01f * 0.01f;
    constexpr float C2 = 0.03f * 0.03f;

    __shared__ float sA[H_IN][W_IN + 1];   // +1 pad: odd row stride
    __shared__ float sB[H_IN][W_IN + 1];
    __shared__ float sH[5][H_IN][TX];      // horizontal-pass results, 5 channels

    const int tid = threadIdx.x;
    const int x0  = blockIdx.x * TX;
    const int y0  = blockIdx.y * TY;
    const int n   = blockIdx.z;
    const float* a0 = img1 + (size_t)n * IMG * IMG;
    const float* b0 = img2 + (size_t)n * IMG * IMG;

    // ---- stage inputs (with zero halo) ----
    for (int i = tid; i < H_IN * W_IN; i += 256) {
        int ry = i / W_IN;
        int rx = i - ry * W_IN;
        int gy = y0 - HALO + ry;
        int gx = x0 - HALO + rx;
        bool ok = (gy >= 0) && (gy < IMG) && (gx >= 0) && (gx < IMG);
        int gi = gy * IMG + gx;
        sA[ry][rx] = ok ? a0[gi] : 0.0f;
        sB[ry][rx] = ok ? b0[gi] : 0.0f;
    }
    __syncthreads();

    // ---- horizontal pass: 5 channels ----
    for (int i = tid; i < H_IN * TX; i += 256) {
        int y = i >> 6;        // /64
        int x = i & 63;
        float m1 = 0.f, m2 = 0.f, q11 = 0.f, q22 = 0.f, q12 = 0.f;
#pragma unroll
        for (int k = 0; k < KW; ++k) {
            float a = sA[y][x + k];
            float b = sB[y][x + k];
            float w = GW[k];
            m1  += w * a;
            m2  += w * b;
            q11 += w * a * a;
            q22 += w * b * b;
            q12 += w * a * b;
        }
        sH[0][y][x] = m1;
        sH[1][y][x] = m2;
        sH[2][y][x] = q11;
        sH[3][y][x] = q22;
        sH[4][y][x] = q12;
    }
    __syncthreads();

    // ---- vertical pass + ssim formula ----
    float sum = 0.0f;
    for (int i = tid; i < TY * TX; i += 256) {
        int y = i >> 6;
        int x = i & 63;
        float mu1 = 0.f, mu2 = 0.f, x11 = 0.f, x22 = 0.f, x12 = 0.f;
#pragma unroll
        for (int j = 0; j < KW; ++j) {
            float w = GW[j];
            mu1 += w * sH[0][y + j][x];
            mu2 += w * sH[1][y + j][x];
            x11 += w * sH[2][y + j][x];
            x22 += w * sH[3][y + j][x];
            x12 += w * sH[4][y + j][x];
        }
        float mu1s = mu1 * mu1;
        float mu2s = mu2 * mu2;
        float mu12 = mu1 * mu2;
        float s1   = x11 - mu1s;
        float s2   = x22 - mu2s;
        float s12  = x12 - mu12;
        float num  = (2.0f * mu12 + C1) * (2.0f * s12 + C2);
        float den  = (mu1s + mu2s + C1) * (s1 + s2 + C2);
        sum += num / den;
    }

    // ---- block reduction (wave64 shuffle, then cross-wave via LDS) ----
#pragma unroll
    for (int off = 32; off > 0; off >>= 1)
        sum += __shfl_down(sum, off, 64);

    __shared__ float wred[4];
    if ((tid & 63) == 0) wred[tid >> 6] = sum;
    __syncthreads();
    if (tid == 0) {
        float s = wred[0] + wred[1] + wred[2] + wred[3];
        atomicAdd(out, -s * (1.0f / NPIX));
    }
}

extern "C" void kernel_launch(void* const* d_in, const int* in_sizes, int n_in,
                              void* d_out, int out_size, void* d_ws, size_t ws_size,
                              hipStream_t stream) {
    const float* img1 = (const float*)d_in[0];
    const float* img2 = (const float*)d_in[1];
    float* out = (float*)d_out;

    ssim_init_out<<<1, 1, 0, stream>>>(out);

    dim3 grid(IMG / TX, IMG / TY, NIMG);   // 8 x 32 x 32 = 8192 blocks
    ssim_tile<<<grid, 256, 0, stream>>>(img1, img2, out);
}